// Round 3
// baseline (61642.474 us; speedup 1.0000x reference)
//
#include <hip/hip_runtime.h>

#define NB 8
#define NS 2048
#define ND 1024
#define NH 1024
#define NWG 128
#define TPB 512
#define HPW 8    /* h-coords per workgroup: NH / NWG */

#define SCOPE_AGENT __HIP_MEMORY_SCOPE_AGENT

__device__ __forceinline__ float sigmf(float v)     { return 1.f / (1.f + __expf(-v)); }
__device__ __forceinline__ float tanh_fast(float v) { return 1.f - 2.f / (1.f + __expf(2.f * v)); }

#define DOT4(acc, W, V)                 \
    acc = fmaf((W).x, (V).x, acc);      \
    acc = fmaf((W).y, (V).y, acc);      \
    acc = fmaf((W).z, (V).z, acc);      \
    acc = fmaf((W).w, (V).w, acc);

__global__ __launch_bounds__(TPB, 2)
void scan_kernel(const float* __restrict__ x,
                 const float* __restrict__ w_ih,
                 const float* __restrict__ w_hh,
                 const float* __restrict__ b_ih,
                 const float* __restrict__ b_hh,
                 const float* __restrict__ thrp,
                 float* __restrict__ membuf,              // 2 * NB*NH floats (double buffer)
                 unsigned long long* __restrict__ bitmap, // NB*NS*(NH/64) words
                 unsigned* __restrict__ bar,              // monotonic group counters
                 float* __restrict__ out_syn,
                 float* __restrict__ out_mem)
{
    __shared__ float x_s2[2][NB * NH / 1];   // wait: 2 x 8192 floats = 64 KB
    __shared__ float m_s[NB * NH];           // 32 KB
    __shared__ float sg[4 * HPW * NB];       // 4 gates x 8 h x 8 b = 1 KB
    __shared__ float c_s[HPW * NB];          // cell state slice

    const int tid  = threadIdx.x;
    const int wg   = blockIdx.x;
    const int hb   = wg * HPW;
    const int wave = tid >> 6;          // 0..7
    const int lane = tid & 63;
    const int g    = wave & 3;          // gate (i,f,g,o)
    const int hh0  = (wave >> 2) * 4;   // h-subblock within WG: 0 or 4
    const int grp  = wg >> 4;           // 8 groups x 16 WGs
    const float thr = *thrp;

    if (tid < HPW * NB) c_s[tid] = 0.f;

    // ---- register-stationary weights: wave owns gate g, rows hb+hh0+rl (rl=0..3)
    // lane's K-slice: {j*256 + lane*4 .. +3 | j=0..3}
    float4 wih[4][4], whh[4][4];
    float bias[4];
    #pragma unroll
    for (int rl = 0; rl < 4; ++rl) {
        const int R = g * NH + hb + hh0 + rl;
        #pragma unroll
        for (int j = 0; j < 4; ++j) {
            wih[rl][j] = *(const float4*)(w_ih + (size_t)R * ND + j * 256 + lane * 4);
            whh[rl][j] = *(const float4*)(w_hh + (size_t)R * NH + j * 256 + lane * 4);
        }
        bias[rl] = b_ih[R] + b_hh[R];
    }

    float xacc[4][NB];   // per-lane PARTIAL x-dots for step t (reduced later with mem part)

    // ---- prologue: prefetch x(0) into buf 0, compute xacc(0)
    {
        #pragma unroll
        for (int j = 0; j < 4; ++j) {
            const int q = wave * 4 + j;               // chunk 0..31 (256 floats each)
            const int b = q >> 2, d = (q & 3) * 256 + lane * 4;
            __builtin_amdgcn_global_load_lds(
                (const __attribute__((address_space(1))) unsigned int*)(x + ((size_t)b * NS + 0) * ND + d),
                (__attribute__((address_space(3))) unsigned int*)&x_s2[0][q * 256],
                16, 0, 0);
        }
        __syncthreads();   // drains vmcnt -> x_s2[0] ready
        #pragma unroll
        for (int b = 0; b < NB; ++b) {
            float4 xv[4];
            #pragma unroll
            for (int j = 0; j < 4; ++j)
                xv[j] = *(const float4*)(&x_s2[0][b * NH + j * 256 + lane * 4]);
            float a0 = 0.f, a1 = 0.f, a2 = 0.f, a3 = 0.f;
            #pragma unroll
            for (int j = 0; j < 4; ++j) {
                DOT4(a0, wih[0][j], xv[j]);
                DOT4(a1, wih[1][j], xv[j]);
                DOT4(a2, wih[2][j], xv[j]);
                DOT4(a3, wih[3][j], xv[j]);
            }
            xacc[0][b] = a0; xacc[1][b] = a1; xacc[2][b] = a2; xacc[3][b] = a3;
        }
    }

    for (int t = 0; t < NS; ++t) {
        const int cur = t & 1, nxt = (t + 1) & 1;
        const float* mcur = membuf + (size_t)cur * (NB * NH);
        float*       mnxt = membuf + (size_t)nxt * (NB * NH);

        // ---- issue prefetch of x(t+1) into buf nxt (fire-and-forget)
        if (t < NS - 1) {
            #pragma unroll
            for (int j = 0; j < 4; ++j) {
                const int q = wave * 4 + j;
                const int b = q >> 2, d = (q & 3) * 256 + lane * 4;
                __builtin_amdgcn_global_load_lds(
                    (const __attribute__((address_space(1))) unsigned int*)(x + ((size_t)b * NS + (t + 1)) * ND + d),
                    (__attribute__((address_space(3))) unsigned int*)&x_s2[nxt][q * 256],
                    16, 0, 0);
            }
        }

        // ---- stage mem(t) via UC (IC-coherent) loads -> LDS
        #pragma unroll
        for (int i = 0; i < 16; ++i) {
            const int f = tid + i * TPB;             // 0..8191
            m_s[f] = __uint_as_float(__hip_atomic_load(
                (const unsigned*)(mcur + f), __ATOMIC_RELAXED, SCOPE_AGENT));
        }
        __syncthreads();

        // ---- mem-part dots, merged reduction with xacc partials
        #pragma unroll
        for (int b = 0; b < NB; ++b) {
            float4 mv[4];
            #pragma unroll
            for (int j = 0; j < 4; ++j)
                mv[j] = *(const float4*)(m_s + b * NH + j * 256 + lane * 4);
            float a0 = xacc[0][b], a1 = xacc[1][b], a2 = xacc[2][b], a3 = xacc[3][b];
            #pragma unroll
            for (int j = 0; j < 4; ++j) {
                DOT4(a0, whh[0][j], mv[j]);
                DOT4(a1, whh[1][j], mv[j]);
                DOT4(a2, whh[2][j], mv[j]);
                DOT4(a3, whh[3][j], mv[j]);
            }
            #pragma unroll
            for (int off = 32; off >= 1; off >>= 1) {
                a0 += __shfl_xor(a0, off);
                a1 += __shfl_xor(a1, off);
                a2 += __shfl_xor(a2, off);
                a3 += __shfl_xor(a3, off);
            }
            if (lane == 0) {
                sg[(g * HPW + hh0 + 0) * NB + b] = a0 + bias[0];
                sg[(g * HPW + hh0 + 1) * NB + b] = a1 + bias[1];
                sg[(g * HPW + hh0 + 2) * NB + b] = a2 + bias[2];
                sg[(g * HPW + hh0 + 3) * NB + b] = a3 + bias[3];
            }
        }
        __syncthreads();

        // ---- pointwise LSTM update: 8 h x 8 b = 64 threads
        if (tid < HPW * NB) {
            const int hl = tid >> 3, b = tid & 7;
            const int h  = hb + hl;
            float gi_v = sg[(0 * HPW + hl) * NB + b];
            float gf_v = sg[(1 * HPW + hl) * NB + b];
            float gg_v = sg[(2 * HPW + hl) * NB + b];
            float go_v = sg[(3 * HPW + hl) * NB + b];
            float c  = c_s[tid];
            float cn = sigmf(gf_v) * c + sigmf(gi_v) * tanh_fast(gg_v);
            float hv = sigmf(go_v) * tanh_fast(cn);
            float mprev = m_s[b * NH + h];
            float reset = (mprev - thr > 0.f) ? 1.f : 0.f;   // snntorch: reset from PREV mem
            float mn = hv - reset * thr;
            c_s[tid] = cn;
            __hip_atomic_store((unsigned*)(mnxt + b * NH + h), __float_as_uint(mn),
                               __ATOMIC_RELAXED, SCOPE_AGENT);
            if (mn - thr > 0.f)
                atomicOr(bitmap + (size_t)(b * NS + t) * (NH / 64) + (h >> 6),
                         1ull << (h & 63));
            if (t == NS - 1) {
                out_syn[b * NH + h] = cn;
                out_mem[b * NH + h] = mn;
            }
        }

        if (t < NS - 1) {
            __syncthreads();              // drain mem stores (vmcnt0) before arriving
            if (tid == 0)
                __hip_atomic_fetch_add(bar + grp * 32, 1u, __ATOMIC_ACQ_REL, SCOPE_AGENT);

            // ---- x-part dots for t+1 (overlaps other WGs' arrival latency)
            #pragma unroll
            for (int b = 0; b < NB; ++b) {
                float4 xv[4];
                #pragma unroll
                for (int j = 0; j < 4; ++j)
                    xv[j] = *(const float4*)(&x_s2[nxt][b * NH + j * 256 + lane * 4]);
                float a0 = 0.f, a1 = 0.f, a2 = 0.f, a3 = 0.f;
                #pragma unroll
                for (int j = 0; j < 4; ++j) {
                    DOT4(a0, wih[0][j], xv[j]);
                    DOT4(a1, wih[1][j], xv[j]);
                    DOT4(a2, wih[2][j], xv[j]);
                    DOT4(a3, wih[3][j], xv[j]);
                }
                xacc[0][b] = a0; xacc[1][b] = a1; xacc[2][b] = a2; xacc[3][b] = a3;
            }

            if (tid == 0) {
                const unsigned want = (unsigned)(NWG) * (unsigned)(t + 1);
                for (;;) {
                    unsigned s0 = 0;
                    #pragma unroll
                    for (int gg = 0; gg < 8; ++gg)
                        s0 += __hip_atomic_load(bar + gg * 32, __ATOMIC_RELAXED, SCOPE_AGENT);
                    if (s0 >= want) break;
                    __builtin_amdgcn_s_sleep(1);
                }
            }
            asm volatile("" ::: "memory");
            __syncthreads();
        }
    }
}

// out[b,s,:] = dyt_w * tanh(alpha * (x + b_fc + spk @ w_fc^T)) + dyt_b
__global__ __launch_bounds__(256)
void out_kernel(const float* __restrict__ x,
                const float* __restrict__ b_fc,
                const float* __restrict__ w_fc,
                const float* __restrict__ alphap,
                const float* __restrict__ dytw,
                const float* __restrict__ dytb,
                const unsigned long long* __restrict__ bitmap,
                float* __restrict__ out)
{
    __shared__ unsigned long long wds[16];
    __shared__ int flag;
    const int row = blockIdx.x;      // b*NS + s
    const int tid = threadIdx.x;
    if (tid < 16) wds[tid] = bitmap[(size_t)row * 16 + tid];
    __syncthreads();
    if (tid == 0) {
        unsigned long long o = 0ull;
        #pragma unroll
        for (int i = 0; i < 16; ++i) o |= wds[i];
        flag = (o != 0ull);
    }
    __syncthreads();

    const float alpha = *alphap;
    const float* xr = x + (size_t)row * NH;
    float* orow = out + (size_t)row * NH;
    const int j0 = tid * 4;

    float4 xv = *(const float4*)(xr + j0);
    float4 bf = *(const float4*)(b_fc + j0);
    float4 dw = *(const float4*)(dytw + j0);
    float4 db = *(const float4*)(dytb + j0);
    float p[4]   = {xv.x, xv.y, xv.z, xv.w};
    float bfa[4] = {bf.x, bf.y, bf.z, bf.w};
    float dwa[4] = {dw.x, dw.y, dw.z, dw.w};
    float dba[4] = {db.x, db.y, db.z, db.w};

    #pragma unroll
    for (int u = 0; u < 4; ++u) {
        float v = p[u] + bfa[u];
        if (flag) {   // general spike path (cold on this data)
            const int j = j0 + u;
            for (int wi = 0; wi < 16; ++wi) {
                unsigned long long m = wds[wi];
                while (m) {
                    int bit = __ffsll(m) - 1;
                    m &= m - 1;
                    v += w_fc[(size_t)j * NH + wi * 64 + bit];
                }
            }
        }
        p[u] = dwa[u] * tanh_fast(alpha * v) + dba[u];
    }
    *(float4*)(orow + j0) = make_float4(p[0], p[1], p[2], p[3]);
}

extern "C" void kernel_launch(void* const* d_in, const int* in_sizes, int n_in,
                              void* d_out, int out_size, void* d_ws, size_t ws_size,
                              hipStream_t stream) {
    const float* x     = (const float*)d_in[0];
    const float* w_ih  = (const float*)d_in[1];
    const float* w_hh  = (const float*)d_in[2];
    const float* b_ih  = (const float*)d_in[3];
    const float* b_hh  = (const float*)d_in[4];
    const float* w_fc  = (const float*)d_in[5];
    const float* b_fc  = (const float*)d_in[6];
    const float* thr   = (const float*)d_in[7];
    const float* alpha = (const float*)d_in[8];
    const float* dytw  = (const float*)d_in[9];
    const float* dytb  = (const float*)d_in[10];

    float* out  = (float*)d_out;
    float* syn  = out + (size_t)NB * NS * NH;
    float* memf = syn + (size_t)NB * NH;

    char* ws = (char*)d_ws;
    unsigned* bar   = (unsigned*)ws;                                  // 4 KB barrier region
    float* membuf   = (float*)(ws + 4096);                            // 64 KB double buffer
    unsigned long long* bitmap = (unsigned long long*)(ws + 4096 + 2 * NB * NH * 4);

    size_t zbytes = 4096 + (size_t)2 * NB * NH * 4
                  + (size_t)NB * NS * (NH / 64) * 8;                  // ~2.17 MB
    (void)hipMemsetAsync(d_ws, 0, zbytes, stream);

    hipLaunchKernelGGL(scan_kernel, dim3(NWG), dim3(TPB), 0, stream,
                       x, w_ih, w_hh, b_ih, b_hh, thr, membuf, bitmap, bar, syn, memf);
    hipLaunchKernelGGL(out_kernel, dim3(NB * NS), dim3(256), 0, stream,
                       x, b_fc, w_fc, alpha, dytw, dytb, bitmap, out);
}